// Round 1
// 160.155 us; speedup vs baseline: 1.0695x; 1.0695x over previous
//
#include <hip/hip_runtime.h>

typedef unsigned long long u64;
typedef unsigned int u32;

#define NN 50000
#define NE 600000
#define D  128
#define WSCALE 262144.0f  // 2^18 fixed-point scale, 24-bit weighted-degree field
#define GH 1172           // hist blocks: ceil(600000/512)
#define GG 391            // gemm blocks: ceil(50000/128)

typedef __attribute__((ext_vector_type(8))) __bf16 bf16x8;
typedef __attribute__((ext_vector_type(8))) unsigned short us8;
typedef __attribute__((ext_vector_type(4))) float f32x4;

__device__ __forceinline__ unsigned short f2bf(float f) {
    u32 u = __float_as_uint(f);
    return (unsigned short)((u + 0x7FFFu + ((u >> 16) & 1u)) >> 16);  // RNE
}
__device__ __forceinline__ float bf2f(unsigned short h) {
    return __uint_as_float((u32)h << 16);
}

// ---------------------------------------------------------------------------
// Fused kernel. Blocks [0, GH): histogram — ONE packed 32-bit atomic per edge:
//   pcnt[c] += (1<<24) | round(w * 2^18)
// high 8 bits = in-degree count (max deg ~40 << 256), low 24 = weighted degree.
// Returned old >> 24 = this edge's rank within its destination bucket.
// Blocks [GH, GH+GG): GEMM h = x @ W^T via split-bf16 MFMA:
//   x = xh + xl, W = Wh + Wl;  h ~= xh*Wh^T + xl*Wh^T + xh*Wl^T  (err ~1e-5)
// Fragments staged in frag-order LDS (conflict-free b128 reads/writes).
// ---------------------------------------------------------------------------
__global__ __launch_bounds__(256) void gemm_hist(
    const float* __restrict__ x, const float* __restrict__ W,
    float* __restrict__ h, const int* __restrict__ col,
    const float* __restrict__ w, u32* __restrict__ pcnt,
    unsigned short* __restrict__ rank, int n) {
    const int t = threadIdx.x;

    if (blockIdx.x < GH) {
        // ---- histogram role: 512 edges per block ----
        const int e0 = blockIdx.x * 512 + t;
#pragma unroll
        for (int s = 0; s < 2; ++s) {
            const int e = e0 + s * 256;
            if (e < NE) {
                const int c = col[e];
                const u32 pack = (1u << 24) | (u32)(w[e] * WSCALE + 0.5f);
                const u32 old = atomicAdd(&pcnt[c], pack);
                rank[e] = (unsigned short)(old >> 24);
            }
        }
        return;
    }

    // ---- GEMM role: 128 rows x 128 cols per block, 4 waves x 32 rows ----
    // frag-order LDS: [op][tile][lane][8 bf16]; op: 0=XH 1=XL 2=WH 3=WL
    __shared__ unsigned short FR[4][8][64][8];  // 32 KB

    const int rb   = (blockIdx.x - GH) * 128;
    const int wv   = t >> 6;   // wave 0..3 owns mtiles {2wv, 2wv+1}
    const int lane = t & 63;

    f32x4 acc[2][8];
#pragma unroll
    for (int m = 0; m < 2; ++m)
#pragma unroll
        for (int nt = 0; nt < 8; ++nt) acc[m][nt] = (f32x4){0.f, 0.f, 0.f, 0.f};

    for (int kc = 0; kc < D; kc += 32) {
        __syncthreads();
        // stage: 512 8-elem chunks each for x and W; 2 per thread.
        // chunk ch -> row r = ch>>2, k-group kg = ch&3.
        // frag slot: tile = r>>4, lane = (kg<<4)|(r&15)  (A: row=lane&15,
        // k=(lane>>4)*8+e; B mirrors with col=lane&15 — same k-permutation
        // for A and B, so any k-order is dot-product invariant).
#pragma unroll
        for (int s = 0; s < 2; ++s) {
            const int ch = s * 256 + t;
            const int r  = ch >> 2;
            const int kg = ch & 3;
            const int ln = (kg << 4) | (r & 15);
            const int tl = r >> 4;
            int rg = rb + r; if (rg >= n) rg = n - 1;
            const float* px = x + (size_t)rg * D + kc + kg * 8;
            float v0[8];
            *(float4*)&v0[0] = *(const float4*)px;
            *(float4*)&v0[4] = *(const float4*)(px + 4);
            us8 hi, lo;
#pragma unroll
            for (int j = 0; j < 8; ++j) {
                const unsigned short hb = f2bf(v0[j]);
                hi[j] = hb;
                lo[j] = f2bf(v0[j] - bf2f(hb));
            }
            *(us8*)&FR[0][tl][ln][0] = hi;
            *(us8*)&FR[1][tl][ln][0] = lo;
            const float* pw = W + (size_t)r * D + kc + kg * 8;
            *(float4*)&v0[0] = *(const float4*)pw;
            *(float4*)&v0[4] = *(const float4*)(pw + 4);
#pragma unroll
            for (int j = 0; j < 8; ++j) {
                const unsigned short hb = f2bf(v0[j]);
                hi[j] = hb;
                lo[j] = f2bf(v0[j] - bf2f(hb));
            }
            *(us8*)&FR[2][tl][ln][0] = hi;
            *(us8*)&FR[3][tl][ln][0] = lo;
        }
        __syncthreads();

        const bf16x8 ah0 = *(const bf16x8*)&FR[0][2 * wv + 0][lane][0];
        const bf16x8 ah1 = *(const bf16x8*)&FR[0][2 * wv + 1][lane][0];
        const bf16x8 al0 = *(const bf16x8*)&FR[1][2 * wv + 0][lane][0];
        const bf16x8 al1 = *(const bf16x8*)&FR[1][2 * wv + 1][lane][0];
#pragma unroll
        for (int nt = 0; nt < 8; ++nt) {
            const bf16x8 bh = *(const bf16x8*)&FR[2][nt][lane][0];
            const bf16x8 bl = *(const bf16x8*)&FR[3][nt][lane][0];
            acc[0][nt] = __builtin_amdgcn_mfma_f32_16x16x32_bf16(ah0, bh, acc[0][nt], 0, 0, 0);
            acc[1][nt] = __builtin_amdgcn_mfma_f32_16x16x32_bf16(ah1, bh, acc[1][nt], 0, 0, 0);
            acc[0][nt] = __builtin_amdgcn_mfma_f32_16x16x32_bf16(al0, bh, acc[0][nt], 0, 0, 0);
            acc[1][nt] = __builtin_amdgcn_mfma_f32_16x16x32_bf16(al1, bh, acc[1][nt], 0, 0, 0);
            acc[0][nt] = __builtin_amdgcn_mfma_f32_16x16x32_bf16(ah0, bl, acc[0][nt], 0, 0, 0);
            acc[1][nt] = __builtin_amdgcn_mfma_f32_16x16x32_bf16(ah1, bl, acc[1][nt], 0, 0, 0);
        }
    }

    // epilogue: C/D layout col = lane&15, row = (lane>>4)*4 + reg (verified)
    const int q = lane >> 4, cl = lane & 15;
#pragma unroll
    for (int m = 0; m < 2; ++m) {
#pragma unroll
        for (int r = 0; r < 4; ++r) {
            const int row = rb + (2 * wv + m) * 16 + q * 4 + r;
            if (row < n) {
                float* o = h + (size_t)row * D + cl;
#pragma unroll
                for (int nt = 0; nt < 8; ++nt) o[nt * 16] = acc[m][nt][r];
            }
        }
    }
}

// ---------------------------------------------------------------------------
// block-local exclusive scan of counts + block totals; also dinv = rsqrt(deg)
__global__ void scan_pass1(const u32* __restrict__ pcnt, int* __restrict__ base,
                           int* __restrict__ btot, float* __restrict__ dinv,
                           int n) {
    __shared__ int s[256];
    const int tid = threadIdx.x;
    const int i = blockIdx.x * 256 + tid;
    int v = 0;
    if (i < n) {
        const u32 p = pcnt[i];
        v = (int)(p >> 24);
        const float degf = 1.0f + (float)(p & 0xFFFFFFu) * (1.0f / WSCALE);
        dinv[i] = rsqrtf(degf);
    }
    s[tid] = v;
    __syncthreads();
    for (int off = 1; off < 256; off <<= 1) {
        int tv = (tid >= off) ? s[tid - off] : 0;
        __syncthreads();
        if (tid >= off) s[tid] += tv;
        __syncthreads();
    }
    if (i < n) base[i] = s[tid] - v;
    if (tid == 255) btot[blockIdx.x] = s[255];
}

__global__ void scan_pass2(int* __restrict__ btot, int nb) {
    __shared__ int s[256];
    const int tid = threadIdx.x;
    const int v = (tid < nb) ? btot[tid] : 0;
    s[tid] = v;
    __syncthreads();
    for (int off = 1; off < 256; off <<= 1) {
        int tv = (tid >= off) ? s[tid - off] : 0;
        __syncthreads();
        if (tid >= off) s[tid] += tv;
        __syncthreads();
    }
    if (tid < nb) btot[tid] = s[tid] - v;
}

// bucket fill, atomic-free: slot = base[c] + btot[c>>8] + rank[e]
__global__ void fill_kernel(const int* __restrict__ row,
                            const int* __restrict__ col,
                            const float* __restrict__ w,
                            const float* __restrict__ dinv,
                            const int* __restrict__ base,
                            const int* __restrict__ btot,
                            const unsigned short* __restrict__ rank,
                            int2* __restrict__ sedge) {
    int e = blockIdx.x * 256 + threadIdx.x;
    if (e < NE) {
        const int r = row[e], c = col[e];
        const int p = base[c] + btot[c >> 8] + (int)rank[e];
        int2 ed;
        ed.x = r;
        ed.y = __float_as_int(dinv[r] * w[e] * dinv[c]);
        sedge[p] = ed;
    }
}

// ---------------------------------------------------------------------------
// one hop: dst[n] = dinv[n]^2 * src[n] + sum_in norm * src[row]
// one HALF-WAVE per node; lane owns 4 columns (float4). Two independent edge
// streams per wave -> 2x in-flight gathers at fixed wave residency, and half
// the gather instructions (1024 B per wave-instruction).
// ---------------------------------------------------------------------------
__global__ __launch_bounds__(256) void hop_kernel(
    const float* __restrict__ src, float* __restrict__ dst,
    const int2* __restrict__ sedge, const int* __restrict__ base,
    const int* __restrict__ btot, const float* __restrict__ dinv) {
    const int node = blockIdx.x * 8 + (threadIdx.x >> 5);
    if (node >= NN) return;
    const int lane = threadIdx.x & 31;
    const float* hl = src + lane * 4;

    const int b = base[node] + btot[node >> 8];
    const int k = (node + 1 < NN)
                      ? (base[node + 1] + btot[(node + 1) >> 8] - b)
                      : (NE - b);

    float4 acc = make_float4(0.f, 0.f, 0.f, 0.f);
#pragma unroll 4
    for (int j = 0; j < k; ++j) {
        const int2 ed = sedge[b + j];
        const float4 hv = *(const float4*)(hl + (size_t)ed.x * D);
        const float nm = __int_as_float(ed.y);
        acc.x = fmaf(nm, hv.x, acc.x);
        acc.y = fmaf(nm, hv.y, acc.y);
        acc.z = fmaf(nm, hv.z, acc.z);
        acc.w = fmaf(nm, hv.w, acc.w);
    }
    const float di = dinv[node];
    const float d2 = di * di;
    const float4 hs = *(const float4*)(hl + (size_t)node * D);
    acc.x = fmaf(d2, hs.x, acc.x);
    acc.y = fmaf(d2, hs.y, acc.y);
    acc.z = fmaf(d2, hs.z, acc.z);
    acc.w = fmaf(d2, hs.w, acc.w);
    *(float4*)(dst + (size_t)node * D + lane * 4) = acc;
}

// ---------------------------------------------------------------------------
extern "C" void kernel_launch(void* const* d_in, const int* in_sizes, int n_in,
                              void* d_out, int out_size, void* d_ws,
                              size_t ws_size, hipStream_t stream) {
    const float* x  = (const float*)d_in[0];
    const int*   ei = (const int*)d_in[1];  // [2, NE]: row then col
    const float* w  = (const float*)d_in[2];
    const float* W  = (const float*)d_in[3];
    float* out = (float*)d_out;

    const int* row = ei;
    const int* col = ei + NE;

    // workspace carve-up (~32.2 MB)
    float* h1   = (float*)d_ws;                    // NN*D floats
    u32*   pcnt = (u32*)(h1 + (size_t)NN * D);     // NN u32
    int*   base = (int*)(pcnt + NN);               // NN
    int*   btot = base + NN;                       // 256
    float* dinv = (float*)(btot + 256);            // NN
    unsigned short* rank = (unsigned short*)(dinv + NN);  // NE u16
    int2*  sedge = (int2*)(rank + NE);             // NE int2

    const int gN = (NN + 255) / 256;  // 196
    const int gE = (NE + 255) / 256;  // 2344
    const int gH = (NN + 7) / 8;      // 6250

    hipMemsetAsync(pcnt, 0, (size_t)NN * sizeof(u32), stream);
    gemm_hist<<<GH + GG, 256, 0, stream>>>(x, W, out, col, w, pcnt, rank, NN);
    scan_pass1<<<gN, 256, 0, stream>>>(pcnt, base, btot, dinv, NN);
    scan_pass2<<<1, 256, 0, stream>>>(btot, gN);
    fill_kernel<<<gE, 256, 0, stream>>>(row, col, w, dinv, base, btot, rank, sedge);

    hop_kernel<<<gH, 256, 0, stream>>>(out, h1, sedge, base, btot, dinv);
    hop_kernel<<<gH, 256, 0, stream>>>(h1, out, sedge, base, btot, dinv);
}

// Round 2
// 154.244 us; speedup vs baseline: 1.1104x; 1.0383x over previous
//
#include <hip/hip_runtime.h>

typedef unsigned long long u64;
typedef unsigned int u32;

#define NN 50000
#define NE 600000
#define D  128
#define WSCALE 262144.0f  // 2^18 fixed-point scale, 24-bit weighted-degree field
#define GH 1172           // hist blocks: ceil(600000/512)
#define GG 391            // gemm blocks: ceil(50000/128)
#define NSTRIP 4          // hop column strips (32 cols each)
#define GS 1563           // hop blocks per strip: ceil(50000/32)

typedef __attribute__((ext_vector_type(8))) __bf16 bf16x8;
typedef __attribute__((ext_vector_type(8))) unsigned short us8;
typedef __attribute__((ext_vector_type(4))) float f32x4;

__device__ __forceinline__ unsigned short f2bf(float f) {
    u32 u = __float_as_uint(f);
    return (unsigned short)((u + 0x7FFFu + ((u >> 16) & 1u)) >> 16);  // RNE
}
__device__ __forceinline__ float bf2f(unsigned short h) {
    return __uint_as_float((u32)h << 16);
}

// ---------------------------------------------------------------------------
// Fused kernel. Blocks [0, GH): histogram — ONE packed 32-bit atomic per edge:
//   pcnt[c] += (1<<24) | round(w * 2^18)
// high 8 bits = in-degree count (max deg ~40 << 256), low 24 = weighted degree.
// Returned old >> 24 = this edge's rank within its destination bucket.
// Blocks [GH, GH+GG): GEMM h = x @ W^T via split-bf16 MFMA:
//   x = xh + xl, W = Wh + Wl;  h ~= xh*Wh^T + xl*Wh^T + xh*Wl^T  (err ~1e-5)
// Fragments staged in frag-order LDS (conflict-free b128 reads/writes).
// ---------------------------------------------------------------------------
__global__ __launch_bounds__(256) void gemm_hist(
    const float* __restrict__ x, const float* __restrict__ W,
    float* __restrict__ h, const int* __restrict__ col,
    const float* __restrict__ w, u32* __restrict__ pcnt,
    unsigned short* __restrict__ rank, int n) {
    const int t = threadIdx.x;

    if (blockIdx.x < GH) {
        // ---- histogram role: 512 edges per block ----
        const int e0 = blockIdx.x * 512 + t;
#pragma unroll
        for (int s = 0; s < 2; ++s) {
            const int e = e0 + s * 256;
            if (e < NE) {
                const int c = col[e];
                const u32 pack = (1u << 24) | (u32)(w[e] * WSCALE + 0.5f);
                const u32 old = atomicAdd(&pcnt[c], pack);
                rank[e] = (unsigned short)(old >> 24);
            }
        }
        return;
    }

    // ---- GEMM role: 128 rows x 128 cols per block, 4 waves x 32 rows ----
    // frag-order LDS: [op][tile][lane][8 bf16]; op: 0=XH 1=XL 2=WH 3=WL
    __shared__ unsigned short FR[4][8][64][8];  // 32 KB

    const int rb   = (blockIdx.x - GH) * 128;
    const int wv   = t >> 6;   // wave 0..3 owns mtiles {2wv, 2wv+1}
    const int lane = t & 63;

    f32x4 acc[2][8];
#pragma unroll
    for (int m = 0; m < 2; ++m)
#pragma unroll
        for (int nt = 0; nt < 8; ++nt) acc[m][nt] = (f32x4){0.f, 0.f, 0.f, 0.f};

    for (int kc = 0; kc < D; kc += 32) {
        __syncthreads();
        // stage: 512 8-elem chunks each for x and W; 2 per thread.
        // chunk ch -> row r = ch>>2, k-group kg = ch&3.
        // frag slot: tile = r>>4, lane = (kg<<4)|(r&15)  (same k-permutation
        // for A and B -> dot-product invariant).
#pragma unroll
        for (int s = 0; s < 2; ++s) {
            const int ch = s * 256 + t;
            const int r  = ch >> 2;
            const int kg = ch & 3;
            const int ln = (kg << 4) | (r & 15);
            const int tl = r >> 4;
            int rg = rb + r; if (rg >= n) rg = n - 1;
            const float* px = x + (size_t)rg * D + kc + kg * 8;
            float v0[8];
            *(float4*)&v0[0] = *(const float4*)px;
            *(float4*)&v0[4] = *(const float4*)(px + 4);
            us8 hi, lo;
#pragma unroll
            for (int j = 0; j < 8; ++j) {
                const unsigned short hb = f2bf(v0[j]);
                hi[j] = hb;
                lo[j] = f2bf(v0[j] - bf2f(hb));
            }
            *(us8*)&FR[0][tl][ln][0] = hi;
            *(us8*)&FR[1][tl][ln][0] = lo;
            const float* pw = W + (size_t)r * D + kc + kg * 8;
            *(float4*)&v0[0] = *(const float4*)pw;
            *(float4*)&v0[4] = *(const float4*)(pw + 4);
#pragma unroll
            for (int j = 0; j < 8; ++j) {
                const unsigned short hb = f2bf(v0[j]);
                hi[j] = hb;
                lo[j] = f2bf(v0[j] - bf2f(hb));
            }
            *(us8*)&FR[2][tl][ln][0] = hi;
            *(us8*)&FR[3][tl][ln][0] = lo;
        }
        __syncthreads();

        const bf16x8 ah0 = *(const bf16x8*)&FR[0][2 * wv + 0][lane][0];
        const bf16x8 ah1 = *(const bf16x8*)&FR[0][2 * wv + 1][lane][0];
        const bf16x8 al0 = *(const bf16x8*)&FR[1][2 * wv + 0][lane][0];
        const bf16x8 al1 = *(const bf16x8*)&FR[1][2 * wv + 1][lane][0];
#pragma unroll
        for (int nt = 0; nt < 8; ++nt) {
            const bf16x8 bh = *(const bf16x8*)&FR[2][nt][lane][0];
            const bf16x8 bl = *(const bf16x8*)&FR[3][nt][lane][0];
            acc[0][nt] = __builtin_amdgcn_mfma_f32_16x16x32_bf16(ah0, bh, acc[0][nt], 0, 0, 0);
            acc[1][nt] = __builtin_amdgcn_mfma_f32_16x16x32_bf16(ah1, bh, acc[1][nt], 0, 0, 0);
            acc[0][nt] = __builtin_amdgcn_mfma_f32_16x16x32_bf16(al0, bh, acc[0][nt], 0, 0, 0);
            acc[1][nt] = __builtin_amdgcn_mfma_f32_16x16x32_bf16(al1, bh, acc[1][nt], 0, 0, 0);
            acc[0][nt] = __builtin_amdgcn_mfma_f32_16x16x32_bf16(ah0, bl, acc[0][nt], 0, 0, 0);
            acc[1][nt] = __builtin_amdgcn_mfma_f32_16x16x32_bf16(ah1, bl, acc[1][nt], 0, 0, 0);
        }
    }

    // epilogue: C/D layout col = lane&15, row = (lane>>4)*4 + reg (verified)
    const int q = lane >> 4, cl = lane & 15;
#pragma unroll
    for (int m = 0; m < 2; ++m) {
#pragma unroll
        for (int r = 0; r < 4; ++r) {
            const int row = rb + (2 * wv + m) * 16 + q * 4 + r;
            if (row < n) {
                float* o = h + (size_t)row * D + cl;
#pragma unroll
                for (int nt = 0; nt < 8; ++nt) o[nt * 16] = acc[m][nt][r];
            }
        }
    }
}

// ---------------------------------------------------------------------------
// block-local exclusive scan of counts + block totals; also dinv = rsqrt(deg)
__global__ void scan_pass1(const u32* __restrict__ pcnt, int* __restrict__ base,
                           int* __restrict__ btot, float* __restrict__ dinv,
                           int n) {
    __shared__ int s[256];
    const int tid = threadIdx.x;
    const int i = blockIdx.x * 256 + tid;
    int v = 0;
    if (i < n) {
        const u32 p = pcnt[i];
        v = (int)(p >> 24);
        const float degf = 1.0f + (float)(p & 0xFFFFFFu) * (1.0f / WSCALE);
        dinv[i] = rsqrtf(degf);
    }
    s[tid] = v;
    __syncthreads();
    for (int off = 1; off < 256; off <<= 1) {
        int tv = (tid >= off) ? s[tid - off] : 0;
        __syncthreads();
        if (tid >= off) s[tid] += tv;
        __syncthreads();
    }
    if (i < n) base[i] = s[tid] - v;
    if (tid == 255) btot[blockIdx.x] = s[255];
}

__global__ void scan_pass2(int* __restrict__ btot, int nb) {
    __shared__ int s[256];
    const int tid = threadIdx.x;
    const int v = (tid < nb) ? btot[tid] : 0;
    s[tid] = v;
    __syncthreads();
    for (int off = 1; off < 256; off <<= 1) {
        int tv = (tid >= off) ? s[tid - off] : 0;
        __syncthreads();
        if (tid >= off) s[tid] += tv;
        __syncthreads();
    }
    if (tid < nb) btot[tid] = s[tid] - v;
}

// bucket fill, atomic-free: slot = base[c] + btot[c>>8] + rank[e]
__global__ void fill_kernel(const int* __restrict__ row,
                            const int* __restrict__ col,
                            const float* __restrict__ w,
                            const float* __restrict__ dinv,
                            const int* __restrict__ base,
                            const int* __restrict__ btot,
                            const unsigned short* __restrict__ rank,
                            int2* __restrict__ sedge) {
    int e = blockIdx.x * 256 + threadIdx.x;
    if (e < NE) {
        const int r = row[e], c = col[e];
        const int p = base[c] + btot[c >> 8] + (int)rank[e];
        int2 ed;
        ed.x = r;
        ed.y = __float_as_int(dinv[r] * w[e] * dinv[c]);
        sedge[p] = ed;
    }
}

// ---------------------------------------------------------------------------
// one hop: dst[n] = dinv[n]^2 * src[n] + sum_in norm * src[row]
// COLUMN-STRIPPED SpMM: blockIdx.y = strip of 32 columns. Active gather
// footprint per strip = 50000 * 128 B = 6.4 MB (~one XCD L2) instead of
// 25.6 MB -> L2 hit rate up. 8-lane groups (float4) = 8 independent edge
// streams per wave. Per-column arithmetic identical to the unstripped
// version (same edges, same order) -> bitwise-same output.
// ---------------------------------------------------------------------------
__global__ __launch_bounds__(256) void hop_kernel(
    const float* __restrict__ src, float* __restrict__ dst,
    const int2* __restrict__ sedge, const int* __restrict__ base,
    const int* __restrict__ btot, const float* __restrict__ dinv) {
    const int node = blockIdx.x * 32 + (threadIdx.x >> 3);
    if (node >= NN) return;
    const int coff = blockIdx.y * 32 + (threadIdx.x & 7) * 4;
    const float* hl = src + coff;

    const int b = base[node] + btot[node >> 8];
    const int k = (node + 1 < NN)
                      ? (base[node + 1] + btot[(node + 1) >> 8] - b)
                      : (NE - b);

    float4 acc = make_float4(0.f, 0.f, 0.f, 0.f);
#pragma unroll 4
    for (int j = 0; j < k; ++j) {
        const int2 ed = sedge[b + j];
        const float4 hv = *(const float4*)(hl + (size_t)ed.x * D);
        const float nm = __int_as_float(ed.y);
        acc.x = fmaf(nm, hv.x, acc.x);
        acc.y = fmaf(nm, hv.y, acc.y);
        acc.z = fmaf(nm, hv.z, acc.z);
        acc.w = fmaf(nm, hv.w, acc.w);
    }
    const float di = dinv[node];
    const float d2 = di * di;
    const float4 hs = *(const float4*)(hl + (size_t)node * D);
    acc.x = fmaf(d2, hs.x, acc.x);
    acc.y = fmaf(d2, hs.y, acc.y);
    acc.z = fmaf(d2, hs.z, acc.z);
    acc.w = fmaf(d2, hs.w, acc.w);
    *(float4*)(dst + (size_t)node * D + coff) = acc;
}

// ---------------------------------------------------------------------------
extern "C" void kernel_launch(void* const* d_in, const int* in_sizes, int n_in,
                              void* d_out, int out_size, void* d_ws,
                              size_t ws_size, hipStream_t stream) {
    const float* x  = (const float*)d_in[0];
    const int*   ei = (const int*)d_in[1];  // [2, NE]: row then col
    const float* w  = (const float*)d_in[2];
    const float* W  = (const float*)d_in[3];
    float* out = (float*)d_out;

    const int* row = ei;
    const int* col = ei + NE;

    // workspace carve-up (~32.2 MB)
    float* h1   = (float*)d_ws;                    // NN*D floats
    u32*   pcnt = (u32*)(h1 + (size_t)NN * D);     // NN u32
    int*   base = (int*)(pcnt + NN);               // NN
    int*   btot = base + NN;                       // 256
    float* dinv = (float*)(btot + 256);            // NN
    unsigned short* rank = (unsigned short*)(dinv + NN);  // NE u16
    int2*  sedge = (int2*)(rank + NE);             // NE int2

    const int gN = (NN + 255) / 256;  // 196
    const int gE = (NE + 255) / 256;  // 2344

    hipMemsetAsync(pcnt, 0, (size_t)NN * sizeof(u32), stream);
    gemm_hist<<<GH + GG, 256, 0, stream>>>(x, W, out, col, w, pcnt, rank, NN);
    scan_pass1<<<gN, 256, 0, stream>>>(pcnt, base, btot, dinv, NN);
    scan_pass2<<<1, 256, 0, stream>>>(btot, gN);
    fill_kernel<<<gE, 256, 0, stream>>>(row, col, w, dinv, base, btot, rank, sedge);

    hop_kernel<<<dim3(GS, NSTRIP), 256, 0, stream>>>(out, h1, sedge, base, btot, dinv);
    hop_kernel<<<dim3(GS, NSTRIP), 256, 0, stream>>>(h1, out, sedge, base, btot, dinv);
}

// Round 3
// 120.670 us; speedup vs baseline: 1.4194x; 1.2782x over previous
//
#include <hip/hip_runtime.h>

typedef unsigned long long u64;
typedef unsigned int u32;
typedef _Float16 f16;

#define NN 50000
#define NE 600000
#define D  128
#define WSCALE 262144.0f  // 2^18 fixed-point scale, 24-bit weighted-degree field
#define NWAVE 3125        // 50000 / 16 rows per wave
#define GGEMM 782         // ceil(3125 / 4 waves per block)
#define GH 1172           // hist blocks: ceil(600000/512)
#define NSTRIP 2          // hop column strips (64 cols fp16 = 128B line each)
#define GS 1563           // hop blocks per strip: ceil(50000/32)

typedef __attribute__((ext_vector_type(8))) __bf16 bf16x8;
typedef __attribute__((ext_vector_type(8))) unsigned short us8;
typedef __attribute__((ext_vector_type(8))) f16 f16x8;
typedef __attribute__((ext_vector_type(4))) float f32x4;

__device__ __forceinline__ unsigned short f2bf(float f) {
    u32 u = __float_as_uint(f);
    return (unsigned short)((u + 0x7FFFu + ((u >> 16) & 1u)) >> 16);  // RNE
}
__device__ __forceinline__ float bf2f(unsigned short h) {
    return __uint_as_float((u32)h << 16);
}

// ---------------------------------------------------------------------------
// prep: zero pcnt AND pre-convert W into frag-order split-bf16 tables.
// chunk i = kc4*512 + nt*64 + lane holds W[nt*16 + (lane&15)][kc4*32 +
// (lane>>4)*8 + e], e=0..7 — exactly the B-fragment the GEMM wave needs, so
// B-loads are lane-contiguous 16B (1KB/wave-instr) and L2-resident.
// ---------------------------------------------------------------------------
__global__ __launch_bounds__(256) void wprep(const float* __restrict__ W,
                                             us8* __restrict__ Whi,
                                             us8* __restrict__ Wlo,
                                             u32* __restrict__ pcnt) {
    const int i = blockIdx.x * 256 + threadIdx.x;
    if (i < NN) pcnt[i] = 0u;
    if (i < 2048) {
        const int lane = i & 63, nt = (i >> 6) & 7, kc4 = i >> 9;
        const float* p =
            W + (size_t)(nt * 16 + (lane & 15)) * D + kc4 * 32 + (lane >> 4) * 8;
        float v[8];
        *(float4*)&v[0] = *(const float4*)p;
        *(float4*)&v[4] = *(const float4*)(p + 4);
        us8 hi, lo;
#pragma unroll
        for (int j = 0; j < 8; ++j) {
            const unsigned short hb = f2bf(v[j]);
            hi[j] = hb;
            lo[j] = f2bf(v[j] - bf2f(hb));
        }
        Whi[i] = hi;
        Wlo[i] = lo;
    }
}

// ---------------------------------------------------------------------------
// Fused kernel. Blocks [0, GGEMM): LDS-free GEMM h16 = fp16(x @ W^T).
//   One wave per 16 output rows. A-frags loaded straight from global
//   (lane l -> row l&15, k (l>>4)*8+e : the wave's 64x32B covers 16 full
//   128B lines), split to hi/lo bf16 in-register; B-frags from the
//   pre-converted Whi/Wlo tables. h ~= xh*Wh^T + xl*Wh^T + xh*Wl^T.
//   Output written ONLY as fp16 strip-major [2][NN][64] (final result is
//   produced by hop2, so no fp32 h is ever needed).
// Blocks [GGEMM, GGEMM+GH): histogram — ONE packed 32-bit atomic per edge:
//   pcnt[c] += (1<<24) | round(w * 2^18);  old>>24 = edge rank in bucket.
// ---------------------------------------------------------------------------
__global__ __launch_bounds__(256) void gemm_hist(
    const float* __restrict__ x, const us8* __restrict__ Whi,
    const us8* __restrict__ Wlo, f16* __restrict__ h16,
    const int* __restrict__ col, const float* __restrict__ w,
    u32* __restrict__ pcnt, unsigned short* __restrict__ rank) {
    const int t = threadIdx.x;

    if (blockIdx.x >= GGEMM) {
        // ---- histogram role: 512 edges per block ----
        const int e0 = (blockIdx.x - GGEMM) * 512 + t;
#pragma unroll
        for (int s = 0; s < 2; ++s) {
            const int e = e0 + s * 256;
            if (e < NE) {
                const int c = col[e];
                const u32 pack = (1u << 24) | (u32)(w[e] * WSCALE + 0.5f);
                const u32 old = atomicAdd(&pcnt[c], pack);
                rank[e] = (unsigned short)(old >> 24);
            }
        }
        return;
    }

    // ---- GEMM role ----
    const int g = blockIdx.x * 4 + (t >> 6);
    if (g >= NWAVE) return;
    const int lane = t & 63;
    const int row0 = g * 16;

    // issue all 8 cold x loads up front (128B per lane, 16 lines per wave)
    const float* px = x + (size_t)(row0 + (lane & 15)) * D + (lane >> 4) * 8;
    float4 ar[8];
#pragma unroll
    for (int c = 0; c < 4; ++c) {
        ar[2 * c]     = *(const float4*)(px + c * 32);
        ar[2 * c + 1] = *(const float4*)(px + c * 32 + 4);
    }

    f32x4 acc[8];
#pragma unroll
    for (int nt = 0; nt < 8; ++nt) acc[nt] = (f32x4){0.f, 0.f, 0.f, 0.f};

#pragma unroll
    for (int c = 0; c < 4; ++c) {
        float v[8];
        *(float4*)&v[0] = ar[2 * c];
        *(float4*)&v[4] = ar[2 * c + 1];
        us8 hiu, lou;
#pragma unroll
        for (int j = 0; j < 8; ++j) {
            const unsigned short hb = f2bf(v[j]);
            hiu[j] = hb;
            lou[j] = f2bf(v[j] - bf2f(hb));
        }
        const bf16x8 ah = *(const bf16x8*)&hiu;
        const bf16x8 al = *(const bf16x8*)&lou;
#pragma unroll
        for (int nt = 0; nt < 8; ++nt) {
            const bf16x8 bh = *(const bf16x8*)&Whi[c * 512 + nt * 64 + lane];
            const bf16x8 bl = *(const bf16x8*)&Wlo[c * 512 + nt * 64 + lane];
            acc[nt] = __builtin_amdgcn_mfma_f32_16x16x32_bf16(ah, bh, acc[nt], 0, 0, 0);
            acc[nt] = __builtin_amdgcn_mfma_f32_16x16x32_bf16(al, bh, acc[nt], 0, 0, 0);
            acc[nt] = __builtin_amdgcn_mfma_f32_16x16x32_bf16(ah, bl, acc[nt], 0, 0, 0);
        }
    }

    // epilogue: C/D layout col = lane&15, row = (lane>>4)*4 + r (verified).
    // store fp16 strip-major: strip = nt>>2, in-strip col = (nt&3)*16 + cl.
    const int q = lane >> 4, cl = lane & 15;
#pragma unroll
    for (int nt = 0; nt < 8; ++nt) {
        f16* o = h16 + (size_t)(nt >> 2) * ((size_t)NN * 64) + (nt & 3) * 16 + cl;
#pragma unroll
        for (int r = 0; r < 4; ++r)
            o[(size_t)(row0 + q * 4 + r) * 64] = (f16)acc[nt][r];
    }
}

// ---------------------------------------------------------------------------
// block-local exclusive scan of counts + block totals; also dinv = rsqrt(deg)
__global__ void scan_pass1(const u32* __restrict__ pcnt, int* __restrict__ base,
                           int* __restrict__ btot, float* __restrict__ dinv,
                           int n) {
    __shared__ int s[256];
    const int tid = threadIdx.x;
    const int i = blockIdx.x * 256 + tid;
    int v = 0;
    if (i < n) {
        const u32 p = pcnt[i];
        v = (int)(p >> 24);
        const float degf = 1.0f + (float)(p & 0xFFFFFFu) * (1.0f / WSCALE);
        dinv[i] = rsqrtf(degf);
    }
    s[tid] = v;
    __syncthreads();
    for (int off = 1; off < 256; off <<= 1) {
        int tv = (tid >= off) ? s[tid - off] : 0;
        __syncthreads();
        if (tid >= off) s[tid] += tv;
        __syncthreads();
    }
    if (i < n) base[i] = s[tid] - v;
    if (tid == 255) btot[blockIdx.x] = s[255];
}

__global__ void scan_pass2(int* __restrict__ btot, int nb) {
    __shared__ int s[256];
    const int tid = threadIdx.x;
    const int v = (tid < nb) ? btot[tid] : 0;
    s[tid] = v;
    __syncthreads();
    for (int off = 1; off < 256; off <<= 1) {
        int tv = (tid >= off) ? s[tid - off] : 0;
        __syncthreads();
        if (tid >= off) s[tid] += tv;
        __syncthreads();
    }
    if (tid < nb) btot[tid] = s[tid] - v;
}

// bucket fill, atomic-free: slot = base[c] + btot[c>>8] + rank[e]
__global__ void fill_kernel(const int* __restrict__ row,
                            const int* __restrict__ col,
                            const float* __restrict__ w,
                            const float* __restrict__ dinv,
                            const int* __restrict__ base,
                            const int* __restrict__ btot,
                            const unsigned short* __restrict__ rank,
                            int2* __restrict__ sedge) {
    int e = blockIdx.x * 256 + threadIdx.x;
    if (e < NE) {
        const int r = row[e], c = col[e];
        const int p = base[c] + btot[c >> 8] + (int)rank[e];
        int2 ed;
        ed.x = r;
        ed.y = __float_as_int(dinv[r] * w[e] * dinv[c]);
        sedge[p] = ed;
    }
}

// ---------------------------------------------------------------------------
// one hop: dst[n] = dinv[n]^2 * src[n] + sum_in norm * src[row]
// fp16 strip-major src [2][NN][64]: each gather is exactly one 128B line.
// 8-lane groups, lane owns 8 cols (16B fp16x8). blockIdx.y = strip.
// OUTF=0: write fp16 strip-major (feeds next hop); OUTF=1: write fp32 out.
// ---------------------------------------------------------------------------
template <int OUTF>
__global__ __launch_bounds__(256) void hop_kernel(
    const f16* __restrict__ src, f16* __restrict__ dst16,
    float* __restrict__ dstf, const int2* __restrict__ sedge,
    const int* __restrict__ base, const int* __restrict__ btot,
    const float* __restrict__ dinv) {
    const int node = blockIdx.x * 32 + (threadIdx.x >> 3);
    if (node >= NN) return;
    const int strip = blockIdx.y;
    const int lo8 = (threadIdx.x & 7) * 8;
    const f16* hs = src + (size_t)strip * ((size_t)NN * 64) + lo8;

    const int b = base[node] + btot[node >> 8];
    const int k = (node + 1 < NN)
                      ? (base[node + 1] + btot[(node + 1) >> 8] - b)
                      : (NE - b);

    float acc[8] = {0.f, 0.f, 0.f, 0.f, 0.f, 0.f, 0.f, 0.f};
#pragma unroll 4
    for (int j = 0; j < k; ++j) {
        const int2 ed = sedge[b + j];
        const f16x8 hv = *(const f16x8*)(hs + (size_t)ed.x * 64);
        const float nm = __int_as_float(ed.y);
#pragma unroll
        for (int i = 0; i < 8; ++i) acc[i] = fmaf(nm, (float)hv[i], acc[i]);
    }
    const float di = dinv[node];
    const float d2 = di * di;
    const f16x8 sv = *(const f16x8*)(hs + (size_t)node * 64);
#pragma unroll
    for (int i = 0; i < 8; ++i) acc[i] = fmaf(d2, (float)sv[i], acc[i]);

    if (OUTF) {
        float* o = dstf + (size_t)node * D + strip * 64 + lo8;
        *(float4*)&o[0] = make_float4(acc[0], acc[1], acc[2], acc[3]);
        *(float4*)&o[4] = make_float4(acc[4], acc[5], acc[6], acc[7]);
    } else {
        f16x8 ov;
#pragma unroll
        for (int i = 0; i < 8; ++i) ov[i] = (f16)acc[i];
        *(f16x8*)(dst16 + (size_t)strip * ((size_t)NN * 64) + (size_t)node * 64 + lo8) = ov;
    }
}

// ---------------------------------------------------------------------------
extern "C" void kernel_launch(void* const* d_in, const int* in_sizes, int n_in,
                              void* d_out, int out_size, void* d_ws,
                              size_t ws_size, hipStream_t stream) {
    const float* x  = (const float*)d_in[0];
    const int*   ei = (const int*)d_in[1];  // [2, NE]: row then col
    const float* w  = (const float*)d_in[2];
    const float* W  = (const float*)d_in[3];
    float* out = (float*)d_out;

    const int* row = ei;
    const int* col = ei + NE;

    // workspace carve-up (~32.3 MB)
    f16* h16a = (f16*)d_ws;                              // 2*NN*64 f16 = 12.8MB
    f16* h16b = h16a + (size_t)2 * NN * 64;              // 12.8MB
    u32* pcnt = (u32*)(h16b + (size_t)2 * NN * 64);      // NN u32
    int* base = (int*)(pcnt + NN);                       // NN
    int* btot = base + NN;                               // 256
    float* dinv = (float*)(btot + 256);                  // NN
    unsigned short* rank = (unsigned short*)(dinv + NN); // NE u16
    int2* sedge = (int2*)(rank + NE);                    // NE int2
    us8* Whi = (us8*)(sedge + NE);                       // 2048 * 16B = 32KB
    us8* Wlo = Whi + 2048;                               // 32KB

    const int gN = (NN + 255) / 256;  // 196
    const int gE = (NE + 255) / 256;  // 2344

    wprep<<<gN, 256, 0, stream>>>(W, Whi, Wlo, pcnt);
    gemm_hist<<<GGEMM + GH, 256, 0, stream>>>(x, Whi, Wlo, h16a, col, w, pcnt, rank);
    scan_pass1<<<gN, 256, 0, stream>>>(pcnt, base, btot, dinv, NN);
    scan_pass2<<<1, 256, 0, stream>>>(btot, gN);
    fill_kernel<<<gE, 256, 0, stream>>>(row, col, w, dinv, base, btot, rank, sedge);

    hop_kernel<0><<<dim3(GS, NSTRIP), 256, 0, stream>>>(h16a, h16b, nullptr,
                                                        sedge, base, btot, dinv);
    hop_kernel<1><<<dim3(GS, NSTRIP), 256, 0, stream>>>(h16b, nullptr, out,
                                                        sedge, base, btot, dinv);
}

// Round 4
// 115.615 us; speedup vs baseline: 1.4815x; 1.0437x over previous
//
#include <hip/hip_runtime.h>

typedef unsigned long long u64;
typedef unsigned int u32;
typedef _Float16 f16;

#define NN 50000
#define NE 600000
#define D  128
#define WSCALE 262144.0f  // 2^18 fixed-point scale, 24-bit weighted-degree field
#define NWAVE 3125        // 50000 / 16 rows per wave
#define GGEMM 782         // ceil(3125 / 4 waves per block)
#define GH4 586           // hist blocks: ceil(600000/1024), 4 edges/thread
#define NSTRIP 2          // hop column strips (64 cols fp16 = 128B line each)
#define GS 1563           // hop blocks per strip: ceil(50000/32)

typedef __attribute__((ext_vector_type(8))) __bf16 bf16x8;
typedef __attribute__((ext_vector_type(8))) unsigned short us8;
typedef __attribute__((ext_vector_type(8))) f16 f16x8;
typedef __attribute__((ext_vector_type(4))) float f32x4;

__device__ __forceinline__ unsigned short f2bf(float f) {
    u32 u = __float_as_uint(f);
    return (unsigned short)((u + 0x7FFFu + ((u >> 16) & 1u)) >> 16);  // RNE
}
__device__ __forceinline__ float bf2f(unsigned short h) {
    return __uint_as_float((u32)h << 16);
}

// ---------------------------------------------------------------------------
// prep: zero pcnt AND pre-convert W into frag-order split-bf16 tables.
// chunk i = kc4*512 + nt*64 + lane holds W[nt*16 + (lane&15)][kc4*32 +
// (lane>>4)*8 + e], e=0..7 — exactly the B-fragment the GEMM wave needs.
// ---------------------------------------------------------------------------
__global__ __launch_bounds__(256) void wprep(const float* __restrict__ W,
                                             us8* __restrict__ Whi,
                                             us8* __restrict__ Wlo,
                                             u32* __restrict__ pcnt) {
    const int i = blockIdx.x * 256 + threadIdx.x;
    if (i < NN) pcnt[i] = 0u;
    if (i < 2048) {
        const int lane = i & 63, nt = (i >> 6) & 7, kc4 = i >> 9;
        const float* p =
            W + (size_t)(nt * 16 + (lane & 15)) * D + kc4 * 32 + (lane >> 4) * 8;
        float v[8];
        *(float4*)&v[0] = *(const float4*)p;
        *(float4*)&v[4] = *(const float4*)(p + 4);
        us8 hi, lo;
#pragma unroll
        for (int j = 0; j < 8; ++j) {
            const unsigned short hb = f2bf(v[j]);
            hi[j] = hb;
            lo[j] = f2bf(v[j] - bf2f(hb));
        }
        Whi[i] = hi;
        Wlo[i] = lo;
    }
}

// ---------------------------------------------------------------------------
// Fused kernel. Blocks [0, GH4): histogram — ONE packed 32-bit atomic/edge,
//   FOUR independent atomic chains per thread (latency overlap):
//   pcnt[c] += (1<<24) | round(w * 2^18);  old>>24 = edge rank in bucket.
// Blocks [GH4, GH4+GGEMM): GEMM h16 = fp16(x @ W^T), one wave / 16 rows.
//   A-frags straight from global (issued before LDS staging so the cold HBM
//   latency hides under it); Whi table (32 KB) staged ONCE per block into
//   LDS (conflict-free b128 frag-order); Wlo read from global, batched 8
//   independent loads per k-chunk. h ~= xh*Wh^T + xl*Wh^T + xh*Wl^T.
//   Output written fp16 strip-major [2][NN][64] only.
// ---------------------------------------------------------------------------
__global__ __launch_bounds__(256) void gemm_hist(
    const float* __restrict__ x, const us8* __restrict__ Whi,
    const us8* __restrict__ Wlo, f16* __restrict__ h16,
    const int* __restrict__ col, const float* __restrict__ w,
    u32* __restrict__ pcnt, unsigned short* __restrict__ rank) {
    const int t = threadIdx.x;

    if (blockIdx.x < GH4) {
        // ---- histogram role: 1024 edges per block, 4 per thread ----
        const int e0 = blockIdx.x * 1024 + t;
#pragma unroll
        for (int s = 0; s < 4; ++s) {
            const int e = e0 + s * 256;
            if (e < NE) {
                const int c = col[e];
                const u32 pack = (1u << 24) | (u32)(w[e] * WSCALE + 0.5f);
                const u32 old = atomicAdd(&pcnt[c], pack);
                rank[e] = (unsigned short)(old >> 24);
            }
        }
        return;
    }

    // ---- GEMM role ----
    __shared__ us8 WH[2048];  // 32 KB: frag-order Whi table, whole K
    const int g = (blockIdx.x - GH4) * 4 + (t >> 6);
    const int lane = t & 63;
    const int gc = (g < NWAVE) ? g : (NWAVE - 1);
    const int row0 = gc * 16;

    // issue all 8 cold x loads up front (128B/lane, 16 full lines per wave)
    const float* px = x + (size_t)(row0 + (lane & 15)) * D + (lane >> 4) * 8;
    float4 ar[8];
#pragma unroll
    for (int c = 0; c < 4; ++c) {
        ar[2 * c]     = *(const float4*)(px + c * 32);
        ar[2 * c + 1] = *(const float4*)(px + c * 32 + 4);
    }

    // stage Whi -> LDS (32 KB, coalesced 16B/thread/iter) while x is in flight
#pragma unroll
    for (int i = 0; i < 8; ++i) WH[t + i * 256] = Whi[t + i * 256];
    __syncthreads();
    if (g >= NWAVE) return;

    f32x4 acc[8];
#pragma unroll
    for (int nt = 0; nt < 8; ++nt) acc[nt] = (f32x4){0.f, 0.f, 0.f, 0.f};

#pragma unroll
    for (int c = 0; c < 4; ++c) {
        // batch the 8 independent Wlo loads for this k-chunk
        bf16x8 blv[8];
#pragma unroll
        for (int nt = 0; nt < 8; ++nt)
            blv[nt] = *(const bf16x8*)&Wlo[c * 512 + nt * 64 + lane];

        float v[8];
        *(float4*)&v[0] = ar[2 * c];
        *(float4*)&v[4] = ar[2 * c + 1];
        us8 hiu, lou;
#pragma unroll
        for (int j = 0; j < 8; ++j) {
            const unsigned short hb = f2bf(v[j]);
            hiu[j] = hb;
            lou[j] = f2bf(v[j] - bf2f(hb));
        }
        const bf16x8 ah = *(const bf16x8*)&hiu;
        const bf16x8 al = *(const bf16x8*)&lou;
#pragma unroll
        for (int nt = 0; nt < 8; ++nt) {
            const bf16x8 bh = *(const bf16x8*)&WH[c * 512 + nt * 64 + lane];
            acc[nt] = __builtin_amdgcn_mfma_f32_16x16x32_bf16(ah, bh, acc[nt], 0, 0, 0);
            acc[nt] = __builtin_amdgcn_mfma_f32_16x16x32_bf16(al, bh, acc[nt], 0, 0, 0);
            acc[nt] = __builtin_amdgcn_mfma_f32_16x16x32_bf16(ah, blv[nt], acc[nt], 0, 0, 0);
        }
    }

    // epilogue: C/D layout col = lane&15, row = (lane>>4)*4 + r (verified).
    // store fp16 strip-major: strip = nt>>2, in-strip col = (nt&3)*16 + cl.
    const int q = lane >> 4, cl = lane & 15;
#pragma unroll
    for (int nt = 0; nt < 8; ++nt) {
        f16* o = h16 + (size_t)(nt >> 2) * ((size_t)NN * 64) + (nt & 3) * 16 + cl;
#pragma unroll
        for (int r = 0; r < 4; ++r)
            o[(size_t)(row0 + q * 4 + r) * 64] = (f16)acc[nt][r];
    }
}

// ---------------------------------------------------------------------------
// block-local exclusive scan of counts + block totals; also dinv = rsqrt(deg)
__global__ void scan_pass1(const u32* __restrict__ pcnt, int* __restrict__ base,
                           int* __restrict__ btot, float* __restrict__ dinv,
                           int n) {
    __shared__ int s[256];
    const int tid = threadIdx.x;
    const int i = blockIdx.x * 256 + tid;
    int v = 0;
    if (i < n) {
        const u32 p = pcnt[i];
        v = (int)(p >> 24);
        const float degf = 1.0f + (float)(p & 0xFFFFFFu) * (1.0f / WSCALE);
        dinv[i] = rsqrtf(degf);
    }
    s[tid] = v;
    __syncthreads();
    for (int off = 1; off < 256; off <<= 1) {
        int tv = (tid >= off) ? s[tid - off] : 0;
        __syncthreads();
        if (tid >= off) s[tid] += tv;
        __syncthreads();
    }
    if (i < n) base[i] = s[tid] - v;
    if (tid == 255) btot[blockIdx.x] = s[255];
}

__global__ void scan_pass2(int* __restrict__ btot, int nb) {
    __shared__ int s[256];
    const int tid = threadIdx.x;
    const int v = (tid < nb) ? btot[tid] : 0;
    s[tid] = v;
    __syncthreads();
    for (int off = 1; off < 256; off <<= 1) {
        int tv = (tid >= off) ? s[tid - off] : 0;
        __syncthreads();
        if (tid >= off) s[tid] += tv;
        __syncthreads();
    }
    if (tid < nb) btot[tid] = s[tid] - v;
}

// bucket fill, atomic-free: slot = base[c] + btot[c>>8] + rank[e]
__global__ void fill_kernel(const int* __restrict__ row,
                            const int* __restrict__ col,
                            const float* __restrict__ w,
                            const float* __restrict__ dinv,
                            const int* __restrict__ base,
                            const int* __restrict__ btot,
                            const unsigned short* __restrict__ rank,
                            int2* __restrict__ sedge) {
    int e = blockIdx.x * 256 + threadIdx.x;
    if (e < NE) {
        const int r = row[e], c = col[e];
        const int p = base[c] + btot[c >> 8] + (int)rank[e];
        int2 ed;
        ed.x = r;
        ed.y = __float_as_int(dinv[r] * w[e] * dinv[c]);
        sedge[p] = ed;
    }
}

// ---------------------------------------------------------------------------
// one hop: dst[n] = dinv[n]^2 * src[n] + sum_in norm * src[row]
// fp16 strip-major src [2][NN][64]: each gather is exactly one 128B line.
// 8-lane groups, lane owns 8 cols (16B fp16x8). blockIdx.y = strip.
// OUTF=0: write fp16 strip-major (feeds next hop); OUTF=1: write fp32 out.
// ---------------------------------------------------------------------------
template <int OUTF>
__global__ __launch_bounds__(256) void hop_kernel(
    const f16* __restrict__ src, f16* __restrict__ dst16,
    float* __restrict__ dstf, const int2* __restrict__ sedge,
    const int* __restrict__ base, const int* __restrict__ btot,
    const float* __restrict__ dinv) {
    const int node = blockIdx.x * 32 + (threadIdx.x >> 3);
    if (node >= NN) return;
    const int strip = blockIdx.y;
    const int lo8 = (threadIdx.x & 7) * 8;
    const f16* hs = src + (size_t)strip * ((size_t)NN * 64) + lo8;

    const int b = base[node] + btot[node >> 8];
    const int k = (node + 1 < NN)
                      ? (base[node + 1] + btot[(node + 1) >> 8] - b)
                      : (NE - b);

    float acc[8] = {0.f, 0.f, 0.f, 0.f, 0.f, 0.f, 0.f, 0.f};
#pragma unroll 4
    for (int j = 0; j < k; ++j) {
        const int2 ed = sedge[b + j];
        const f16x8 hv = *(const f16x8*)(hs + (size_t)ed.x * 64);
        const float nm = __int_as_float(ed.y);
#pragma unroll
        for (int i = 0; i < 8; ++i) acc[i] = fmaf(nm, (float)hv[i], acc[i]);
    }
    const float di = dinv[node];
    const float d2 = di * di;
    const f16x8 sv = *(const f16x8*)(hs + (size_t)node * 64);
#pragma unroll
    for (int i = 0; i < 8; ++i) acc[i] = fmaf(d2, (float)sv[i], acc[i]);

    if (OUTF) {
        float* o = dstf + (size_t)node * D + strip * 64 + lo8;
        *(float4*)&o[0] = make_float4(acc[0], acc[1], acc[2], acc[3]);
        *(float4*)&o[4] = make_float4(acc[4], acc[5], acc[6], acc[7]);
    } else {
        f16x8 ov;
#pragma unroll
        for (int i = 0; i < 8; ++i) ov[i] = (f16)acc[i];
        *(f16x8*)(dst16 + (size_t)strip * ((size_t)NN * 64) + (size_t)node * 64 + lo8) = ov;
    }
}

// ---------------------------------------------------------------------------
extern "C" void kernel_launch(void* const* d_in, const int* in_sizes, int n_in,
                              void* d_out, int out_size, void* d_ws,
                              size_t ws_size, hipStream_t stream) {
    const float* x  = (const float*)d_in[0];
    const int*   ei = (const int*)d_in[1];  // [2, NE]: row then col
    const float* w  = (const float*)d_in[2];
    const float* W  = (const float*)d_in[3];
    float* out = (float*)d_out;

    const int* row = ei;
    const int* col = ei + NE;

    // workspace carve-up (~32.3 MB)
    f16* h16a = (f16*)d_ws;                              // 2*NN*64 f16 = 12.8MB
    f16* h16b = h16a + (size_t)2 * NN * 64;              // 12.8MB
    u32* pcnt = (u32*)(h16b + (size_t)2 * NN * 64);      // NN u32
    int* base = (int*)(pcnt + NN);                       // NN
    int* btot = base + NN;                               // 256
    float* dinv = (float*)(btot + 256);                  // NN
    unsigned short* rank = (unsigned short*)(dinv + NN); // NE u16
    int2* sedge = (int2*)(rank + NE);                    // NE int2
    us8* Whi = (us8*)(sedge + NE);                       // 2048 * 16B = 32KB
    us8* Wlo = Whi + 2048;                               // 32KB

    const int gN = (NN + 255) / 256;  // 196
    const int gE = (NE + 255) / 256;  // 2344

    wprep<<<gN, 256, 0, stream>>>(W, Whi, Wlo, pcnt);
    gemm_hist<<<GH4 + GGEMM, 256, 0, stream>>>(x, Whi, Wlo, h16a, col, w, pcnt, rank);
    scan_pass1<<<gN, 256, 0, stream>>>(pcnt, base, btot, dinv, NN);
    scan_pass2<<<1, 256, 0, stream>>>(btot, gN);
    fill_kernel<<<gE, 256, 0, stream>>>(row, col, w, dinv, base, btot, rank, sedge);

    hop_kernel<0><<<dim3(GS, NSTRIP), 256, 0, stream>>>(h16a, h16b, nullptr,
                                                        sedge, base, btot, dinv);
    hop_kernel<1><<<dim3(GS, NSTRIP), 256, 0, stream>>>(h16b, nullptr, out,
                                                        sedge, base, btot, dinv);
}

// Round 5
// 107.787 us; speedup vs baseline: 1.5891x; 1.0726x over previous
//
#include <hip/hip_runtime.h>

typedef unsigned long long u64;
typedef unsigned int u32;
typedef _Float16 f16;

#define NN 50000
#define NE 600000
#define D  128
#define NWAVE 3125        // 50000 / 16 rows per GEMM wave
#define GGEMM 782         // ceil(3125 / 4 waves per block)
#define EPB 2048          // edges per partition-pass block (8 per thread)
#define NB_P 293          // ceil(600000 / 2048)
#define NP 196            // partitions: col >> 8 (256 nodes each)
#define NSTRIP 2          // hop column strips (64 cols fp16 = 128B line each)
#define GS 1563           // hop blocks per strip: ceil(50000/32)

typedef __attribute__((ext_vector_type(8))) __bf16 bf16x8;
typedef __attribute__((ext_vector_type(8))) unsigned short us8;
typedef __attribute__((ext_vector_type(8))) f16 f16x8;
typedef __attribute__((ext_vector_type(4))) float f32x4;

__device__ __forceinline__ unsigned short f2bf(float f) {
    u32 u = __float_as_uint(f);
    return (unsigned short)((u + 0x7FFFu + ((u >> 16) & 1u)) >> 16);  // RNE
}
__device__ __forceinline__ float bf2f(unsigned short h) {
    return __uint_as_float((u32)h << 16);
}

// ---------------------------------------------------------------------------
// prep: pre-convert W into frag-order split-bf16 tables (2048 chunks).
// chunk i = kc4*512 + nt*64 + lane holds W[nt*16 + (lane&15)][kc4*32 +
// (lane>>4)*8 + e], e=0..7 — exactly the B-fragment the GEMM wave needs.
// ---------------------------------------------------------------------------
__global__ __launch_bounds__(256) void wprep(const float* __restrict__ W,
                                             us8* __restrict__ Whi,
                                             us8* __restrict__ Wlo) {
    const int i = blockIdx.x * 256 + threadIdx.x;
    if (i < 2048) {
        const int lane = i & 63, nt = (i >> 6) & 7, kc4 = i >> 9;
        const float* p =
            W + (size_t)(nt * 16 + (lane & 15)) * D + kc4 * 32 + (lane >> 4) * 8;
        float v[8];
        *(float4*)&v[0] = *(const float4*)p;
        *(float4*)&v[4] = *(const float4*)(p + 4);
        us8 hi, lo;
#pragma unroll
        for (int j = 0; j < 8; ++j) {
            const unsigned short hb = f2bf(v[j]);
            hi[j] = hb;
            lo[j] = f2bf(v[j] - bf2f(hb));
        }
        Whi[i] = hi;
        Wlo[i] = lo;
    }
}

// ---------------------------------------------------------------------------
// Fused kernel. Blocks [0, NB_P): partition COUNT — per-block 196-bin LDS
//   histogram of col>>8 over its 2048 edges; write cnt[p][b]. LDS atomics
//   only — NO device atomics (round-4 counters showed each returning device
//   atomic generated ~32B of HBM write traffic; 600k of them were the wall).
// Blocks [NB_P, NB_P+GGEMM): GEMM h16 = fp16(x @ W^T), one wave / 16 rows,
//   split-bf16 MFMA (h ~= xh*Wh^T + xl*Wh^T + xh*Wl^T), Whi staged once to
//   LDS, output fp16 strip-major [2][NN][64].
// ---------------------------------------------------------------------------
__global__ __launch_bounds__(256) void gemm_count(
    const float* __restrict__ x, const us8* __restrict__ Whi,
    const us8* __restrict__ Wlo, f16* __restrict__ h16,
    const int* __restrict__ col, int* __restrict__ cnt) {
    const int t = threadIdx.x;
    __shared__ us8 WH[2048];  // 32 KB (GEMM role); reused as bins (count role)

    if (blockIdx.x < NB_P) {
        // ---- partition-count role ----
        int* bins = (int*)WH;
        for (int i = t; i < NP; i += 256) bins[i] = 0;
        __syncthreads();
        const int e0 = blockIdx.x * EPB + t;
#pragma unroll
        for (int s = 0; s < 8; ++s) {
            const int e = e0 + s * 256;
            if (e < NE) atomicAdd(&bins[col[e] >> 8], 1);
        }
        __syncthreads();
        for (int i = t; i < NP; i += 256)
            cnt[i * NB_P + blockIdx.x] = bins[i];
        return;
    }

    // ---- GEMM role ----
    const int g = (blockIdx.x - NB_P) * 4 + (t >> 6);
    const int lane = t & 63;
    const int gc = (g < NWAVE) ? g : (NWAVE - 1);
    const int row0 = gc * 16;

    // issue all 8 cold x loads up front (128B/lane, 16 full lines per wave)
    const float* px = x + (size_t)(row0 + (lane & 15)) * D + (lane >> 4) * 8;
    float4 ar[8];
#pragma unroll
    for (int c = 0; c < 4; ++c) {
        ar[2 * c]     = *(const float4*)(px + c * 32);
        ar[2 * c + 1] = *(const float4*)(px + c * 32 + 4);
    }

    // stage Whi -> LDS (32 KB, coalesced) while x loads are in flight
#pragma unroll
    for (int i = 0; i < 8; ++i) WH[t + i * 256] = Whi[t + i * 256];
    __syncthreads();
    if (g >= NWAVE) return;

    f32x4 acc[8];
#pragma unroll
    for (int nt = 0; nt < 8; ++nt) acc[nt] = (f32x4){0.f, 0.f, 0.f, 0.f};

#pragma unroll
    for (int c = 0; c < 4; ++c) {
        bf16x8 blv[8];
#pragma unroll
        for (int nt = 0; nt < 8; ++nt)
            blv[nt] = *(const bf16x8*)&Wlo[c * 512 + nt * 64 + lane];

        float v[8];
        *(float4*)&v[0] = ar[2 * c];
        *(float4*)&v[4] = ar[2 * c + 1];
        us8 hiu, lou;
#pragma unroll
        for (int j = 0; j < 8; ++j) {
            const unsigned short hb = f2bf(v[j]);
            hiu[j] = hb;
            lou[j] = f2bf(v[j] - bf2f(hb));
        }
        const bf16x8 ah = *(const bf16x8*)&hiu;
        const bf16x8 al = *(const bf16x8*)&lou;
#pragma unroll
        for (int nt = 0; nt < 8; ++nt) {
            const bf16x8 bh = *(const bf16x8*)&WH[c * 512 + nt * 64 + lane];
            acc[nt] = __builtin_amdgcn_mfma_f32_16x16x32_bf16(ah, bh, acc[nt], 0, 0, 0);
            acc[nt] = __builtin_amdgcn_mfma_f32_16x16x32_bf16(al, bh, acc[nt], 0, 0, 0);
            acc[nt] = __builtin_amdgcn_mfma_f32_16x16x32_bf16(ah, blv[nt], acc[nt], 0, 0, 0);
        }
    }

    // epilogue: C/D layout col = lane&15, row = (lane>>4)*4 + r (verified).
    const int q = lane >> 4, cl = lane & 15;
#pragma unroll
    for (int nt = 0; nt < 8; ++nt) {
        f16* o = h16 + (size_t)(nt >> 2) * ((size_t)NN * 64) + (nt & 3) * 16 + cl;
#pragma unroll
        for (int r = 0; r < 4; ++r)
            o[(size_t)(row0 + q * 4 + r) * 64] = (f16)acc[nt][r];
    }
}

// ---------------------------------------------------------------------------
// K2: per-partition exclusive scan over the NB_P block-counts (in place),
// one block per partition; 512-slot scan with 256 threads (2 elems each).
__global__ __launch_bounds__(256) void scan_blocks(int* __restrict__ cnt,
                                                   int* __restrict__ totals) {
    __shared__ int sw[256];
    const int p = blockIdx.x, tid = threadIdx.x;
    const int i0 = 2 * tid, i1 = 2 * tid + 1;
    const int a0 = (i0 < NB_P) ? cnt[p * NB_P + i0] : 0;
    const int a1 = (i1 < NB_P) ? cnt[p * NB_P + i1] : 0;
    const int pair = a0 + a1;
    sw[tid] = pair;
    __syncthreads();
    for (int off = 1; off < 256; off <<= 1) {
        int tv = (tid >= off) ? sw[tid - off] : 0;
        __syncthreads();
        if (tid >= off) sw[tid] += tv;
        __syncthreads();
    }
    const int excl = sw[tid] - pair;
    if (i0 < NB_P) cnt[p * NB_P + i0] = excl;
    if (i1 < NB_P) cnt[p * NB_P + i1] = excl + a0;
    if (tid == 255) totals[p] = sw[255];
}

// K3: scan partition totals -> binbase; also base[NN] = NE sentinel.
__global__ __launch_bounds__(256) void scan_parts(const int* __restrict__ totals,
                                                  int* __restrict__ binbase,
                                                  int* __restrict__ base) {
    __shared__ int sw[256];
    const int tid = threadIdx.x;
    const int v = (tid < NP) ? totals[tid] : 0;
    sw[tid] = v;
    __syncthreads();
    for (int off = 1; off < 256; off <<= 1) {
        int tv = (tid >= off) ? sw[tid - off] : 0;
        __syncthreads();
        if (tid >= off) sw[tid] += tv;
        __syncthreads();
    }
    if (tid < NP) binbase[tid] = sw[tid] - v;
    if (tid == NP - 1) {
        binbase[NP] = sw[tid];  // == NE
        base[NN] = sw[tid];
    }
}

// ---------------------------------------------------------------------------
// K4: scatter edges into partition-contiguous part[] (u64: w|row|colloc).
// slot = binbase[p] + cursor[p][block] + LDS-local-rank. No device atomics.
__global__ __launch_bounds__(256) void scatter_k(
    const int* __restrict__ row, const int* __restrict__ col,
    const float* __restrict__ w, const int* __restrict__ cnt,
    const int* __restrict__ binbase, u64* __restrict__ part) {
    __shared__ int bins[NP];
    __shared__ int off0[NP];
    const int b = blockIdx.x, t = threadIdx.x;
    for (int i = t; i < NP; i += 256) {
        bins[i] = 0;
        off0[i] = binbase[i] + cnt[i * NB_P + b];
    }
    __syncthreads();
    const int e0 = b * EPB + t;
#pragma unroll
    for (int s = 0; s < 8; ++s) {
        const int e = e0 + s * 256;
        if (e < NE) {
            const int c = col[e];
            const int p = c >> 8;
            const int lr = atomicAdd(&bins[p], 1);
            part[off0[p] + lr] = ((u64)__float_as_uint(w[e]) << 32) |
                                 ((u32)row[e] << 8) | (u32)(c & 255);
        }
    }
}

// ---------------------------------------------------------------------------
// K5: per-partition CSR finish. Block p owns nodes [p*256, p*256+256) and
// edges [binbase[p], binbase[p+1]). LDS count + float weighted-degree ->
// dinv; LDS scan -> absolute base[node]; scatter to sedge with partial
// norm w * dinv[col].
__global__ __launch_bounds__(256) void csr_k(
    const u64* __restrict__ part, const int* __restrict__ binbase,
    int* __restrict__ base, float* __restrict__ dinv,
    int2* __restrict__ sedge) {
    __shared__ u32 cntL[256];
    __shared__ float wsL[256];   // weighted degree, then reused as dinv
    __shared__ int curL[256];
    __shared__ int sw[256];
    const int p = blockIdx.x, tid = threadIdx.x;
    const int eb = binbase[p], ee = binbase[p + 1];

    cntL[tid] = 0u;
    wsL[tid] = 0.f;
    __syncthreads();
    for (int e = eb + tid; e < ee; e += 256) {
        const u64 pk = part[e];
        const int cl = (int)(pk & 255u);
        atomicAdd(&cntL[cl], 1u);
        atomicAdd(&wsL[cl], __uint_as_float((u32)(pk >> 32)));
    }
    __syncthreads();

    const int node = p * 256 + tid;
    const float di = rsqrtf(1.0f + wsL[tid]);  // deg = 1 (self) + sum_in w
    const int myc = (int)cntL[tid];
    sw[tid] = myc;
    __syncthreads();
    for (int off = 1; off < 256; off <<= 1) {
        int tv = (tid >= off) ? sw[tid - off] : 0;
        __syncthreads();
        if (tid >= off) sw[tid] += tv;
        __syncthreads();
    }
    const int excl = sw[tid] - myc;
    if (node < NN) {
        dinv[node] = di;
        base[node] = eb + excl;
    }
    __syncthreads();
    wsL[tid] = di;     // now holds dinv for this partition's nodes
    curL[tid] = excl;  // partition-local cursor
    __syncthreads();

    for (int e = eb + tid; e < ee; e += 256) {
        const u64 pk = part[e];
        const int cl = (int)(pk & 255u);
        const int r = (int)((pk >> 8) & 0xFFFFu);
        const float wv = __uint_as_float((u32)(pk >> 32));
        const int lr = atomicAdd(&curL[cl], 1);
        int2 ed;
        ed.x = r;
        ed.y = __float_as_int(wv * wsL[cl]);  // partial norm: w * dinv[col]
        sedge[eb + lr] = ed;
    }
}

// K6: finalize norm: ed.y *= dinv[row]
__global__ __launch_bounds__(256) void norm_k(int2* __restrict__ sedge,
                                              const float* __restrict__ dinv) {
    const int e = blockIdx.x * 256 + threadIdx.x;
    if (e < NE) {
        const int2 ed = sedge[e];
        sedge[e].y = __float_as_int(__int_as_float(ed.y) * dinv[ed.x]);
    }
}

// ---------------------------------------------------------------------------
// one hop: dst[n] = dinv[n]^2 * src[n] + sum_in norm * src[row]
// fp16 strip-major src [2][NN][64]: each gather is exactly one 128B line.
// 8-lane groups, lane owns 8 cols (16B fp16x8). blockIdx.y = strip.
// OUTF=0: write fp16 strip-major (feeds next hop); OUTF=1: write fp32 out.
// ---------------------------------------------------------------------------
template <int OUTF>
__global__ __launch_bounds__(256) void hop_kernel(
    const f16* __restrict__ src, f16* __restrict__ dst16,
    float* __restrict__ dstf, const int2* __restrict__ sedge,
    const int* __restrict__ base, const float* __restrict__ dinv) {
    const int node = blockIdx.x * 32 + (threadIdx.x >> 3);
    if (node >= NN) return;
    const int strip = blockIdx.y;
    const int lo8 = (threadIdx.x & 7) * 8;
    const f16* hs = src + (size_t)strip * ((size_t)NN * 64) + lo8;

    const int b = base[node];
    const int k = base[node + 1] - b;

    float acc[8] = {0.f, 0.f, 0.f, 0.f, 0.f, 0.f, 0.f, 0.f};
#pragma unroll 4
    for (int j = 0; j < k; ++j) {
        const int2 ed = sedge[b + j];
        const f16x8 hv = *(const f16x8*)(hs + (size_t)ed.x * 64);
        const float nm = __int_as_float(ed.y);
#pragma unroll
        for (int i = 0; i < 8; ++i) acc[i] = fmaf(nm, (float)hv[i], acc[i]);
    }
    const float di = dinv[node];
    const float d2 = di * di;
    const f16x8 sv = *(const f16x8*)(hs + (size_t)node * 64);
#pragma unroll
    for (int i = 0; i < 8; ++i) acc[i] = fmaf(d2, (float)sv[i], acc[i]);

    if (OUTF) {
        float* o = dstf + (size_t)node * D + strip * 64 + lo8;
        *(float4*)&o[0] = make_float4(acc[0], acc[1], acc[2], acc[3]);
        *(float4*)&o[4] = make_float4(acc[4], acc[5], acc[6], acc[7]);
    } else {
        f16x8 ov;
#pragma unroll
        for (int i = 0; i < 8; ++i) ov[i] = (f16)acc[i];
        *(f16x8*)(dst16 + (size_t)strip * ((size_t)NN * 64) + (size_t)node * 64 + lo8) = ov;
    }
}

// ---------------------------------------------------------------------------
extern "C" void kernel_launch(void* const* d_in, const int* in_sizes, int n_in,
                              void* d_out, int out_size, void* d_ws,
                              size_t ws_size, hipStream_t stream) {
    const float* x  = (const float*)d_in[0];
    const int*   ei = (const int*)d_in[1];  // [2, NE]: row then col
    const float* w  = (const float*)d_in[2];
    const float* W  = (const float*)d_in[3];
    float* out = (float*)d_out;

    const int* row = ei;
    const int* col = ei + NE;

    // workspace carve-up (~31.1 MB)
    f16* h16a = (f16*)d_ws;                          // 2*NN*64 f16 = 12.8MB
    f16* h16b = h16a + (size_t)2 * NN * 64;          // 12.8MB
    u64* part = (u64*)h16b;                          // 4.8MB alias (dead before hop1)
    us8* Whi = (us8*)(h16b + (size_t)2 * NN * 64);   // 32KB
    us8* Wlo = Whi + 2048;                           // 32KB
    int* cnt = (int*)(Wlo + 2048);                   // NP*NB_P ints (230KB)
    int* totals = cnt + NP * NB_P;                   // NP
    int* binbase = totals + NP;                      // NP+1
    int* base = binbase + NP + 1;                    // NN+1
    float* dinv = (float*)(base + NN + 1);           // NN
    int2* sedge = (int2*)(dinv + NN);                // NE int2 = 4.8MB

    const int gE = (NE + 255) / 256;  // 2344

    hipMemsetAsync(cnt, 0, (size_t)NP * NB_P * sizeof(int), stream);
    wprep<<<8, 256, 0, stream>>>(W, Whi, Wlo);
    gemm_count<<<NB_P + GGEMM, 256, 0, stream>>>(x, Whi, Wlo, h16a, col, cnt);
    scan_blocks<<<NP, 256, 0, stream>>>(cnt, totals);
    scan_parts<<<1, 256, 0, stream>>>(totals, binbase, base);
    scatter_k<<<NB_P, 256, 0, stream>>>(row, col, w, cnt, binbase, part);
    csr_k<<<NP, 256, 0, stream>>>(part, binbase, base, dinv, sedge);
    norm_k<<<gE, 256, 0, stream>>>(sedge, dinv);

    hop_kernel<0><<<dim3(GS, NSTRIP), 256, 0, stream>>>(h16a, h16b, nullptr,
                                                        sedge, base, dinv);
    hop_kernel<1><<<dim3(GS, NSTRIP), 256, 0, stream>>>(h16b, nullptr, out,
                                                        sedge, base, dinv);
}